// Round 1
// baseline (5283.197 us; speedup 1.0000x reference)
//
#include <hip/hip_runtime.h>

// Sizes (fixed by the problem)
#define DZc 512
#define Bc  64
#define Tc  1000
#define TPc 1008   // padded T so 16-row tiles divide evenly (63 tiles)
#define DUc 16
#define DXc 256

// Workspace layout (requires ~66.9 MB):
//   Wp  : bf16 W packed in MFMA B-fragment order   262144 ushort (512 KB)
//   Bp  : bf16 B_obs packed in B-fragment order    131072 ushort (256 KB)
//   zs  : bf16 z-history [B][TP][DZ]               64*1008*512 ushort (66 MB)

typedef __attribute__((ext_vector_type(4))) float f32x4;
typedef __attribute__((ext_vector_type(8))) short s16x8;

__device__ __forceinline__ unsigned short f2bf(float x) {
  unsigned u = __builtin_bit_cast(unsigned, x);
  u = u + 0x7FFFu + ((u >> 16) & 1u);   // round-to-nearest-even
  return (unsigned short)(u >> 16);
}

// Pack W[512][512] (row = output i, col = input j) into bf16 MFMA B-fragments.
// Fragment (kt,nt): lane l element j holds B[k][n] = W[n][k],
//   n = nt*16 + (l&15), k = kt*32 + (l>>4)*8 + j.
// Linear layout: Wp[((kt*32 + nt)*64 + l)*8 + j]
__global__ void pack_w_kernel(const float* __restrict__ W,
                              unsigned short* __restrict__ Wp) {
  int d = blockIdx.x * 256 + threadIdx.x;          // 262144 total
  int j = d & 7, l = (d >> 3) & 63, nt = (d >> 9) & 31, kt = d >> 14;
  int n = nt * 16 + (l & 15);
  int k = kt * 32 + ((l >> 4) << 3) + j;
  Wp[d] = f2bf(W[n * DZc + k]);
}

// Pack B_obs[512][256] ([z][x]) into bf16 B-fragments: B[k][n] = B_obs[k][n].
// Layout: Bp[((kt*16 + nt)*64 + l)*8 + j], nt in [0,16), kt in [0,16)
__global__ void pack_b_kernel(const float* __restrict__ B,
                              unsigned short* __restrict__ Bp) {
  int d = blockIdx.x * 256 + threadIdx.x;          // 131072 total
  int j = d & 7, l = (d >> 3) & 63, nt = (d >> 9) & 15, kt = d >> 13;
  int n = nt * 16 + (l & 15);
  int k = kt * 32 + ((l >> 4) << 3) + j;
  Bp[d] = f2bf(B[k * DXc + n]);
}

// Zero the t = 1000..1007 pad rows of zs so projection A-tiles read zeros.
__global__ void zero_pad_kernel(unsigned short* __restrict__ zs) {
  int d = blockIdx.x * 256 + threadIdx.x;          // 64*8*512 = 262144
  int i = d & 511, tt = (d >> 9) & 7, b = d >> 12;
  zs[((size_t)b * TPc + Tc + tt) * DZc + i] = 0;
}

// Recurrence: one WG (512 threads = 8 waves) per trial. z kept in LDS (f32).
// Per step: a = bf16(relu(z-h)) staged in LDS; each wave owns 4 n-tiles
// (64 outputs) and streams its W fragments from L2; MFMA with A = broadcast(a).
// Since A and B fragments use the SAME k formula, the k lane-mapping cancels.
__global__ __launch_bounds__(512, 1) void rnn_rec_kernel(
    const float* __restrict__ z0, const float* __restrict__ v,
    const float* __restrict__ Wu, const float* __restrict__ h,
    const float* __restrict__ dp, const unsigned short* __restrict__ Wp,
    unsigned short* __restrict__ zs) {
  __shared__ float z_lds[DZc];
  __shared__ float h_lds[DZc];
  __shared__ float wut[DUc][DZc];                 // Wu transposed, 32 KB
  __shared__ float v_lds[DUc];
  __shared__ __align__(16) unsigned short a_lds[DZc];

  const int tid = threadIdx.x;
  const int b = blockIdx.x;
  const int lane = tid & 63;
  const int w = tid >> 6;                          // wave 0..7
  const int l15 = lane & 15;
  const int lg = lane >> 4;

  // ---- one-time staging ----
  z_lds[tid] = z0[b * DZc + tid];
  h_lds[tid] = h[tid];
  {
    const f32x4* wu4 = (const f32x4*)(Wu + tid * DUc);
#pragma unroll
    for (int kk = 0; kk < 4; ++kk) {
      f32x4 q = wu4[kk];
#pragma unroll
      for (int e = 0; e < 4; ++e) wut[kk * 4 + e][tid] = q[e];
    }
  }
  const float decay = expf(-expf(dp[0]));

  // wave w reads n-tiles w*4 .. w*4+3; frag (kt,ntg) at ((kt*32+ntg)*64+lane)*8
  const unsigned short* wbase = Wp + (size_t)((w * 4) * 64 + lane) * 8;
  unsigned short* zrow = zs + (size_t)b * TPc * DZc;

  for (int t = 0; t < Tc; ++t) {
    __syncthreads();                               // prev-step z writes done
    if (tid < DUc) v_lds[tid] = v[(b * DUc + tid) * Tc + t];
    {
      float zz = z_lds[tid];
      float av = zz - h_lds[tid];
      a_lds[tid] = f2bf(av > 0.f ? av : 0.f);
    }
    __syncthreads();                               // a_lds / v_lds ready

    f32x4 acc[4];
#pragma unroll
    for (int n = 0; n < 4; ++n)
#pragma unroll
      for (int e = 0; e < 4; ++e) acc[n][e] = 0.f;

#pragma unroll
    for (int kt = 0; kt < 16; ++kt) {
      s16x8 af = *(const s16x8*)&a_lds[kt * 32 + lg * 8];  // broadcast A rows
#pragma unroll
      for (int n = 0; n < 4; ++n) {
        s16x8 bf = *(const s16x8*)(wbase + (size_t)kt * 16384 + n * 512);
        acc[n] = __builtin_amdgcn_mfma_f32_16x16x32_bf16(af, bf, acc[n], 0, 0, 0);
      }
    }

    // Epilogue: rows of D are identical (broadcast A), use reg 0 on lg==0 lanes.
    if (lg == 0) {
#pragma unroll
      for (int n = 0; n < 4; ++n) {
        int gi = w * 64 + n * 16 + l15;
        float inp = 0.f;
#pragma unroll
        for (int k = 0; k < DUc; ++k) inp += wut[k][gi] * v_lds[k];
        float val = decay * z_lds[gi] + acc[n][0] + inp;
        z_lds[gi] = val;
        zrow[(size_t)t * DZc + gi] = f2bf(val);
      }
    }
  }
}

// Projection: x[b][xo][t] = sum_z B_obs[z][xo] * zs[b][z][t] + Bias[xo].
// One WG (256 thr = 4 waves) per (b, 16-t tile). Wave w owns n-tiles w*4..w*4+3.
// D rows (m) are consecutive t; regs r are t..t+3 -> float4 store.
__global__ __launch_bounds__(256, 1) void rnn_proj_kernel(
    const unsigned short* __restrict__ zs, const unsigned short* __restrict__ Bp,
    const float* __restrict__ Bias, float* __restrict__ x) {
  const int wg = blockIdx.x;                       // 64*63 = 4032
  const int b = wg / 63;
  const int tbase = (wg % 63) * 16;
  const int tid = threadIdx.x;
  const int lane = tid & 63;
  const int w = tid >> 6;
  const int l15 = lane & 15, lg = lane >> 4;

  const unsigned short* abase =
      zs + ((size_t)b * TPc + tbase + l15) * DZc + lg * 8;

  f32x4 acc[4];
#pragma unroll
  for (int n = 0; n < 4; ++n)
#pragma unroll
    for (int e = 0; e < 4; ++e) acc[n][e] = 0.f;

#pragma unroll
  for (int kt = 0; kt < 16; ++kt) {
    s16x8 af = *(const s16x8*)(abase + kt * 32);
#pragma unroll
    for (int n = 0; n < 4; ++n) {
      s16x8 bf = *(const s16x8*)(Bp + (size_t)((kt * 16 + w * 4 + n) * 64 + lane) * 8);
      acc[n] = __builtin_amdgcn_mfma_f32_16x16x32_bf16(af, bf, acc[n], 0, 0, 0);
    }
  }

  const int t = tbase + lg * 4;                    // regs cover t..t+3
  if (t < Tc) {
#pragma unroll
    for (int n = 0; n < 4; ++n) {
      int xo = (w * 4 + n) * 16 + l15;
      float bias = Bias[xo];
      f32x4 val = acc[n];
#pragma unroll
      for (int e = 0; e < 4; ++e) val[e] += bias;
      *(f32x4*)(x + ((size_t)b * DXc + xo) * Tc + t) = val;
    }
  }
}

extern "C" void kernel_launch(void* const* d_in, const int* in_sizes, int n_in,
                              void* d_out, int out_size, void* d_ws, size_t ws_size,
                              hipStream_t stream) {
  const float* z0   = (const float*)d_in[0];
  const float* v    = (const float*)d_in[1];
  const float* W    = (const float*)d_in[2];
  const float* Wu   = (const float*)d_in[3];
  const float* h    = (const float*)d_in[4];
  const float* dp   = (const float*)d_in[5];
  const float* Bo   = (const float*)d_in[6];
  const float* Bias = (const float*)d_in[7];
  float* x = (float*)d_out;

  unsigned short* Wp = (unsigned short*)d_ws;          // 262144 ushort
  unsigned short* Bp = Wp + 262144;                    // 131072 ushort
  unsigned short* zs = Wp + 262144 + 131072;           // 64*1008*512 ushort

  pack_w_kernel<<<1024, 256, 0, stream>>>(W, Wp);
  pack_b_kernel<<<512, 256, 0, stream>>>(Bo, Bp);
  zero_pad_kernel<<<1024, 256, 0, stream>>>(zs);
  rnn_rec_kernel<<<64, 512, 0, stream>>>(z0, v, Wu, h, dp, Wp, zs);
  rnn_proj_kernel<<<4032, 256, 0, stream>>>(zs, Bp, Bias, x);
}

// Round 2
// 2075.260 us; speedup vs baseline: 2.5458x; 2.5458x over previous
//
#include <hip/hip_runtime.h>

// Sizes (fixed by the problem)
#define DZc 512
#define Bc  64
#define Tc  1000
#define DUc 16
#define DXc 256

#define KTOT 17            // 16 W k-tiles + 1 augmented (Wu, v hi/lo) tile
#define NFRAG (KTOT * 4)   // 68 fragments per wave (4 n-tiles each)
#define NREG  51           // fragments held in VGPRs per wave
#define NLDS  (NFRAG - NREG) // 17 fragments per wave in LDS (136 KB total)
#define AROW  552          // padded activation row length (bf16 elems)

// Workspace layout:
//   Wp : bf16 augmented W' [544 k][512 n] in B-fragment order  278528 ushort
//   Bp : bf16 B_obs in B-fragment order                        131072 ushort
//   zs : bf16 z-history [T][B][DZ]                             32768000 ushort
// total = 66.36 MB (< previous round's 66.85 MB usage)

typedef __attribute__((ext_vector_type(4))) float f32x4;
typedef __attribute__((ext_vector_type(8))) short s16x8;

__device__ __forceinline__ unsigned short f2bf(float x) {
  unsigned u = __builtin_bit_cast(unsigned, x);
  u = u + 0x7FFFu + ((u >> 16) & 1u);   // round-to-nearest-even
  return (unsigned short)(u >> 16);
}
__device__ __forceinline__ float bf2f(unsigned short u) {
  unsigned x = ((unsigned)u) << 16;
  return __builtin_bit_cast(float, x);
}

// Pack augmented W' into bf16 MFMA B-fragments.
// W'[n][k]: k<512 -> W[n][k]; k in [512,544) -> Wu[n][k&15] (appears twice:
// A-side supplies v_hi for k in [512,528) and v_lo for [528,544)).
// Fragment (kt,nt): lane l elem j holds B[k][n], n = nt*16+(l&15),
// k = kt*32+(l>>4)*8+j.  Linear: Wp[((kt*32+nt)*64+l)*8+j]
__global__ void pack_w_kernel(const float* __restrict__ W,
                              const float* __restrict__ Wu,
                              unsigned short* __restrict__ Wp) {
  int d = blockIdx.x * 256 + threadIdx.x;          // 278528 total
  int j = d & 7, l = (d >> 3) & 63, nt = (d >> 9) & 31, kt = d >> 14;
  int n = nt * 16 + (l & 15);
  int k = kt * 32 + ((l >> 4) << 3) + j;
  float val = (k < DZc) ? W[n * DZc + k] : Wu[n * DUc + (k & 15)];
  Wp[d] = f2bf(val);
}

// Pack B_obs[512][256] ([z][x]) into bf16 B-fragments: B[k][n] = B_obs[k][n].
__global__ void pack_b_kernel(const float* __restrict__ B,
                              unsigned short* __restrict__ Bp) {
  int d = blockIdx.x * 256 + threadIdx.x;          // 131072 total
  int j = d & 7, l = (d >> 3) & 63, nt = (d >> 9) & 15, kt = d >> 13;
  int n = nt * 16 + (l & 15);
  int k = kt * 32 + ((l >> 4) << 3) + j;
  Bp[d] = f2bf(B[k * DXc + n]);
}

// Recurrence: 4 WGs, each 512 threads (8 waves) handling 16 trials with the
// ENTIRE W resident per CU: 51 frags/wave in VGPRs + 17 frags/wave in LDS.
// z state lives in the MFMA accumulator registers. Per step: write
// a = bf16(relu(z-h)) + v hi/lo rows to LDS, scale acc by decay, run
// 68 MFMAs (17 kt x 4 nt) adding W@a + Wu@v, store z bf16 to zs.
__global__ __launch_bounds__(512, 2) void rnn_rec_kernel(
    const float* __restrict__ z0, const float* __restrict__ v,
    const float* __restrict__ h, const float* __restrict__ dp,
    const unsigned short* __restrict__ Wp, unsigned short* __restrict__ zs) {
  __shared__ unsigned short wlds[8][NLDS][512];    // [wave][frag][lane*8] 136 KB
  __shared__ unsigned short a_lds[16][AROW];       // [trial][k] 17.25 KB

  const int tid = threadIdx.x;
  const int lane = tid & 63;
  const int w = tid >> 6;
  const int l15 = lane & 15;
  const int lg = lane >> 4;
  const int b0 = blockIdx.x * 16;

  // ---- one-time: load W fragments (regs + LDS) ----
  s16x8 wr[NREG];
#pragma unroll
  for (int c = 0; c < NFRAG; ++c) {
    int kt = c >> 2, nt = c & 3;
    s16x8 f = *(const s16x8*)(Wp + ((size_t)((kt * 32 + w * 4 + nt) * 64 + lane)) * 8);
    if (c < NREG) wr[c] = f;
    else *(s16x8*)&wlds[w][c - NREG][lane * 8] = f;
  }

  // ---- one-time: z0 into acc, h into regs ----
  float hreg[4];
  f32x4 acc[4];
#pragma unroll
  for (int nt = 0; nt < 4; ++nt) {
    hreg[nt] = h[w * 64 + nt * 16 + l15];
#pragma unroll
    for (int r = 0; r < 4; ++r)
      acc[nt][r] = z0[(size_t)(b0 + lg * 4 + r) * DZc + w * 64 + nt * 16 + l15];
  }
  const float decay = expf(-expf(dp[0]));

  // v staging: threads 0..255 each own one (trial, du) slot
  const int du = tid & 15, trr = tid >> 4;
  const size_t vbase = ((size_t)(b0 + trr) * DUc + du) * Tc;
  float vcur = (tid < 256) ? v[vbase] : 0.f;

  // zs [t][b][dz]: base for (t=0, r=0, nt=0); 16 stores use imm offsets
  unsigned short* zbase = zs + (size_t)(b0 + lg * 4) * DZc + w * 64 + l15;

  for (int t = 0; t < Tc; ++t) {
    __syncthreads();                               // prev A-reads done
    // activations: slot (nt,r) -> trial = lg*4+r, out = w*64+nt*16+l15
#pragma unroll
    for (int nt = 0; nt < 4; ++nt)
#pragma unroll
      for (int r = 0; r < 4; ++r) {
        float av = acc[nt][r] - hreg[nt];
        av = av > 0.f ? av : 0.f;
        a_lds[lg * 4 + r][w * 64 + nt * 16 + l15] = f2bf(av);
      }
    if (tid < 256) {                               // v hi/lo rows (k 512..543)
      unsigned short hi = f2bf(vcur);
      float rem = vcur - bf2f(hi);
      a_lds[trr][512 + du] = hi;
      a_lds[trr][528 + du] = f2bf(rem);
    }
    // prefetch next step's v (hides HBM/L2 latency under MFMA phase)
    float vnext = (tid < 256) ? v[vbase + (t + 1 < Tc ? t + 1 : Tc - 1)] : 0.f;
#pragma unroll
    for (int nt = 0; nt < 4; ++nt)
#pragma unroll
      for (int r = 0; r < 4; ++r) acc[nt][r] *= decay;
    __syncthreads();                               // a_lds ready

#pragma unroll
    for (int kt = 0; kt < KTOT; ++kt) {
      s16x8 af = *(const s16x8*)&a_lds[l15][kt * 32 + lg * 8];
#pragma unroll
      for (int nt = 0; nt < 4; ++nt) {
        int c = kt * 4 + nt;
        s16x8 bf;
        if (c < NREG) bf = wr[c];
        else bf = *(const s16x8*)&wlds[w][c - NREG][lane * 8];
        acc[nt] = __builtin_amdgcn_mfma_f32_16x16x32_bf16(af, bf, acc[nt], 0, 0, 0);
      }
    }

    // store z_{t+1} (acc) to zs[t][b][dz]
#pragma unroll
    for (int nt = 0; nt < 4; ++nt)
#pragma unroll
      for (int r = 0; r < 4; ++r)
        zbase[r * DZc + nt * 16] = f2bf(acc[nt][r]);
    zbase += Bc * DZc;
    vcur = vnext;
  }
}

// Projection: x[b][xo][t] = sum_z B_obs[z][xo] * zs[t][b][z] + Bias[xo].
// One WG (256 thr = 4 waves) per (b, 16-t tile); 63 tiles (last masked).
__global__ __launch_bounds__(256, 1) void rnn_proj_kernel(
    const unsigned short* __restrict__ zs, const unsigned short* __restrict__ Bp,
    const float* __restrict__ Bias, float* __restrict__ x) {
  const int wg = blockIdx.x;                       // 64*63 = 4032
  const int b = wg / 63;
  const int tbase = (wg % 63) * 16;
  const int tid = threadIdx.x;
  const int lane = tid & 63;
  const int w = tid >> 6;
  const int l15 = lane & 15, lg = lane >> 4;

  const int trow = tbase + l15;
  const int trc = trow < Tc ? trow : Tc - 1;
  const unsigned short* abase = zs + ((size_t)trc * Bc + b) * DZc + lg * 8;
  const s16x8 zz = {0, 0, 0, 0, 0, 0, 0, 0};

  f32x4 acc[4];
#pragma unroll
  for (int n = 0; n < 4; ++n)
#pragma unroll
    for (int e = 0; e < 4; ++e) acc[n][e] = 0.f;

#pragma unroll
  for (int kt = 0; kt < 16; ++kt) {
    s16x8 af = *(const s16x8*)(abase + kt * 32);
    af = (trow < Tc) ? af : zz;                    // mask pad t-rows
#pragma unroll
    for (int n = 0; n < 4; ++n) {
      s16x8 bf = *(const s16x8*)(Bp + (size_t)((kt * 16 + w * 4 + n) * 64 + lane) * 8);
      acc[n] = __builtin_amdgcn_mfma_f32_16x16x32_bf16(af, bf, acc[n], 0, 0, 0);
    }
  }

  const int t = tbase + lg * 4;                    // regs cover t..t+3
  if (t < Tc) {
#pragma unroll
    for (int n = 0; n < 4; ++n) {
      int xo = (w * 4 + n) * 16 + l15;
      float bias = Bias[xo];
      f32x4 val = acc[n];
#pragma unroll
      for (int e = 0; e < 4; ++e) val[e] += bias;
      *(f32x4*)(x + ((size_t)b * DXc + xo) * Tc + t) = val;
    }
  }
}

extern "C" void kernel_launch(void* const* d_in, const int* in_sizes, int n_in,
                              void* d_out, int out_size, void* d_ws, size_t ws_size,
                              hipStream_t stream) {
  const float* z0   = (const float*)d_in[0];
  const float* v    = (const float*)d_in[1];
  const float* W    = (const float*)d_in[2];
  const float* Wu   = (const float*)d_in[3];
  const float* h    = (const float*)d_in[4];
  const float* dp   = (const float*)d_in[5];
  const float* Bo   = (const float*)d_in[6];
  const float* Bias = (const float*)d_in[7];
  float* x = (float*)d_out;

  unsigned short* Wp = (unsigned short*)d_ws;          // 278528 ushort
  unsigned short* Bp = Wp + 278528;                    // 131072 ushort
  unsigned short* zs = Bp + 131072;                    // 1000*64*512 ushort

  pack_w_kernel<<<1088, 256, 0, stream>>>(W, Wu, Wp);
  pack_b_kernel<<<512, 256, 0, stream>>>(Bo, Bp);
  rnn_rec_kernel<<<4, 512, 0, stream>>>(z0, v, h, dp, Wp, zs);
  rnn_proj_kernel<<<4032, 256, 0, stream>>>(zs, Bp, Bias, x);
}